// Round 2
// baseline (213.113 us; speedup 1.0000x reference)
//
#include <hip/hip_runtime.h>

// Problem constants (from the reference)
#define S_      7
#define SS_     49
#define B_      2
#define C_      20
#define F_      30                 // B*5 + C
#define N_IMG_  16384
#define NCELL_  (N_IMG_ * SS_)     // 802816
#define NPAIR_  (NCELL_ / 2)       // 401408 cell-pairs; 1 pair = 480 B = 15 float4
#define COORD_  5.0f
#define NOOBJ_  0.5f

#define TPB           256
#define GRID          512                      // 2 blocks/CU -> persistent
#define PAIRS_PER_IT  (GRID * TPB)             // 131072 pairs = 63 MB window/iter
#define NIT           ((NPAIR_ + PAIRS_PER_IT - 1) / PAIRS_PER_IT)   // 4

__device__ __forceinline__ float iou8(float px, float py, float pw, float ph,
                                      float tx, float ty, float tw, float th) {
    float xA = fmaxf(px - pw * 0.5f, tx - tw * 0.5f);
    float yA = fmaxf(py - ph * 0.5f, ty - th * 0.5f);
    float xB = fminf(px + pw * 0.5f, tx + tw * 0.5f);
    float yB = fminf(py + ph * 0.5f, ty + th * 0.5f);
    float inter = fmaxf(0.f, xB - xA) * fmaxf(0.f, yB - yA);
    float areaA = pw * ph;
    float areaB = tw * th;
    return inter / (areaA + areaB - inter);
}

// All indices into p/q are compile-time constants after inlining -> stays in VGPRs.
__device__ __forceinline__ float cell_loss(const float* p, const float* q) {
    // NOOBJ * sum((p_conf - t_conf)^2) over both boxes, all cells
    float d0 = p[20] - q[20];
    float d1 = p[21] - q[21];
    float l = NOOBJ_ * (d0 * d0 + d1 * d1);

    if (q[20] > 0.f) {          // obj cell
        // class-prob term
        float sprob = 0.f;
        #pragma unroll
        for (int f = 0; f < C_; ++f) {
            float d = p[f] - q[f];
            sprob += d * d;
        }
        l += sprob;

        // responsible box via IoU argmax (first max wins -> strict >)
        float i0 = iou8(p[22], p[23], p[24], p[25], q[22], q[23], q[24], q[25]);
        float i1 = iou8(p[26], p[27], p[28], p[29], q[26], q[27], q[28], q[29]);
        bool b1 = i1 > i0;

        // confidence term for responsible box (select, not dynamic index)
        float pc = b1 ? p[21] : p[20];
        float tc = b1 ? q[21] : q[20];
        float dc = pc - tc;
        l += (1.0f - NOOBJ_) * dc * dc;

        // coord term (obj=true so tb_wh == tb[2:4])
        float pb0 = b1 ? p[26] : p[22];
        float pb1 = b1 ? p[27] : p[23];
        float pb2 = b1 ? p[28] : p[24];
        float pb3 = b1 ? p[29] : p[25];
        float tb0 = b1 ? q[26] : q[22];
        float tb1 = b1 ? q[27] : q[23];
        float tb2 = b1 ? q[28] : q[24];
        float tb3 = b1 ? q[29] : q[25];
        float bx = pb0 - tb0;
        float by = pb1 - tb1;
        float bw = sqrtf(pb2) - sqrtf(tb2);
        float bh = sqrtf(pb3) - sqrtf(tb3);
        l += COORD_ * (bx * bx + by * by + bw * bw + bh * bh);
    }
    return l;
}

__global__ __launch_bounds__(TPB, 2) void mploss_kernel(
        const float* __restrict__ preds,
        const float* __restrict__ targets,
        float* __restrict__ out) {
    __shared__ float s_red[TPB / 64];

    const int tid  = threadIdx.x;
    const int lane = tid & 63;
    const int wave = tid >> 6;

    const int base0 = blockIdx.x * TPB + tid;   // pair offset within each sweep

    float l = 0.f;

    // Persistent grid-stride sweep: per iteration the whole grid covers a
    // contiguous, forward-moving 63 MB window of both arrays (DRAM row
    // locality), instead of exposing all 192 MB at once.
    for (int it = 0; it < NIT; ++it) {
        const long pair = (long)it * PAIRS_PER_IT + base0;
        if (pair < NPAIR_) {                    // block-uniform (boundary is block-aligned)
            const float4* p4 = (const float4*)preds   + pair * 15;
            const float4* t4 = (const float4*)targets + pair * 15;

            union { float4 v[15]; float f[60]; } P, T;
            #pragma unroll
            for (int i = 0; i < 15; ++i) P.v[i] = p4[i];
            #pragma unroll
            for (int i = 0; i < 15; ++i) T.v[i] = t4[i];

            l += cell_loss(P.f,      T.f)
               + cell_loss(P.f + 30, T.f + 30);
        }
    }

    // wave (64-lane) shuffle reduction
    #pragma unroll
    for (int off = 32; off > 0; off >>= 1)
        l += __shfl_down(l, off, 64);

    if (lane == 0) s_red[wave] = l;
    __syncthreads();
    if (tid == 0) {
        float tot = s_red[0] + s_red[1] + s_red[2] + s_red[3];
        atomicAdd(out, tot * (1.0f / (float)N_IMG_));
    }
}

extern "C" void kernel_launch(void* const* d_in, const int* in_sizes, int n_in,
                              void* d_out, int out_size, void* d_ws, size_t ws_size,
                              hipStream_t stream) {
    const float* preds   = (const float*)d_in[0];
    const float* targets = (const float*)d_in[1];
    float* out = (float*)d_out;

    // d_out is poisoned 0xAA before every launch; zero it (graph-capture safe)
    hipMemsetAsync(out, 0, sizeof(float) * (size_t)out_size, stream);

    mploss_kernel<<<GRID, TPB, 0, stream>>>(preds, targets, out);
}

// Round 3
// 208.783 us; speedup vs baseline: 1.0207x; 1.0207x over previous
//
#include <hip/hip_runtime.h>

// Problem constants (from the reference)
#define S_      7
#define SS_     49
#define B_      2
#define C_      20
#define F_      30                 // B*5 + C
#define N_IMG_  16384
#define NCELL_  (N_IMG_ * SS_)     // 802816
#define NPAIR_  (NCELL_ / 2)       // 401408 cell-pairs; 1 pair = 480 B = 15 float4
#define COORD_  5.0f
#define NOOBJ_  0.5f

#define TPB   256
#define NBLK  (NPAIR_ / TPB)       // 1568 exactly

// Pair-block float4 layout (floats 0..59, f4 #k = floats 4k..4k+3):
//   cell0: probs f0-19 (#0-#4) | conf f20,21 (#5.x,.y) | box f22-29 (#5.z,.w  #6  #7.x,.y)
//   cell1: probs f30-49 (#7.z,.w  #8-#11  #12.x,.y) | conf f50,51 (#12.z,.w) | box f52-59 (#13 #14)
// Conf words (#5, #12) are loaded unconditionally; everything else only for
// obj lanes (exec-masked loads -> non-obj lanes fetch no lines for them).

__device__ __forceinline__ float iou8(float px, float py, float pw, float ph,
                                      float tx, float ty, float tw, float th) {
    float xA = fmaxf(px - pw * 0.5f, tx - tw * 0.5f);
    float yA = fmaxf(py - ph * 0.5f, ty - th * 0.5f);
    float xB = fminf(px + pw * 0.5f, tx + tw * 0.5f);
    float yB = fminf(py + ph * 0.5f, ty + th * 0.5f);
    float inter = fmaxf(0.f, xB - xA) * fmaxf(0.f, yB - yA);
    float areaA = pw * ph;
    float areaB = tw * th;
    return inter / (areaA + areaB - inter);
}

#define ACC4(A, B) do {                         \
    float d_;                                   \
    d_ = (A).x - (B).x; sp += d_ * d_;          \
    d_ = (A).y - (B).y; sp += d_ * d_;          \
    d_ = (A).z - (B).z; sp += d_ * d_;          \
    d_ = (A).w - (B).w; sp += d_ * d_;          \
} while (0)

__global__ __launch_bounds__(TPB) void mploss_kernel(
        const float* __restrict__ preds,
        const float* __restrict__ targets,
        float* __restrict__ out) {
    __shared__ float s_red[TPB / 64];

    const int tid  = threadIdx.x;
    const int lane = tid & 63;
    const int wave = tid >> 6;

    const long pair = (long)blockIdx.x * TPB + tid;
    const float4* p4 = (const float4*)preds   + pair * 15;
    const float4* t4 = (const float4*)targets + pair * 15;

    // Unconditional: the two conf-carrying words of each array (64 B/lane).
    float4 P5  = p4[5],  T5  = t4[5];
    float4 P12 = p4[12], T12 = t4[12];

    const bool obj0 = T5.x  > 0.f;    // t_conf[cell0, 0]
    const bool obj1 = T12.z > 0.f;    // t_conf[cell1, 0]

    // NOOBJ * sum((p_conf - t_conf)^2), both boxes, both cells
    float l;
    {
        float d0 = P5.x  - T5.x,  d1 = P5.y  - T5.y;
        float d2 = P12.z - T12.z, d3 = P12.w - T12.w;
        l = NOOBJ_ * (d0 * d0 + d1 * d1 + d2 * d2 + d3 * d3);
    }

    if (obj0) {
        float4 A0 = p4[0], A1 = p4[1], A2 = p4[2], A3 = p4[3], A4 = p4[4];
        float4 A6 = p4[6], A7 = p4[7];
        float4 B0 = t4[0], B1 = t4[1], B2 = t4[2], B3 = t4[3], B4 = t4[4];
        float4 B6 = t4[6], B7 = t4[7];

        // class-prob term: floats 0..19
        float sp = 0.f;
        ACC4(A0, B0); ACC4(A1, B1); ACC4(A2, B2); ACC4(A3, B3); ACC4(A4, B4);
        l += sp;

        // responsible box via IoU argmax (first max wins -> strict >)
        float i0 = iou8(P5.z, P5.w, A6.x, A6.y,  T5.z, T5.w, B6.x, B6.y);
        float i1 = iou8(A6.z, A6.w, A7.x, A7.y,  B6.z, B6.w, B7.x, B7.y);
        bool b1 = i1 > i0;

        float pc = b1 ? P5.y : P5.x;
        float tc = b1 ? T5.y : T5.x;
        float dc = pc - tc;
        l += (1.0f - NOOBJ_) * dc * dc;

        float px = b1 ? A6.z : P5.z,  py = b1 ? A6.w : P5.w;
        float pw = b1 ? A7.x : A6.x,  ph = b1 ? A7.y : A6.y;
        float tx = b1 ? B6.z : T5.z,  ty = b1 ? B6.w : T5.w;
        float tw = b1 ? B7.x : B6.x,  th = b1 ? B7.y : B6.y;
        float bx = px - tx;
        float by = py - ty;
        float bw = sqrtf(pw) - sqrtf(tw);
        float bh = sqrtf(ph) - sqrtf(th);
        l += COORD_ * (bx * bx + by * by + bw * bw + bh * bh);
    }

    if (obj1) {
        float4 A7 = p4[7], A8 = p4[8], A9 = p4[9], A10 = p4[10], A11 = p4[11];
        float4 A13 = p4[13], A14 = p4[14];
        float4 B7 = t4[7], B8 = t4[8], B9 = t4[9], B10 = t4[10], B11 = t4[11];
        float4 B13 = t4[13], B14 = t4[14];

        // class-prob term: floats 30..49
        float sp = 0.f, d_;
        d_ = A7.z - B7.z; sp += d_ * d_;
        d_ = A7.w - B7.w; sp += d_ * d_;
        ACC4(A8, B8); ACC4(A9, B9); ACC4(A10, B10); ACC4(A11, B11);
        d_ = P12.x - T12.x; sp += d_ * d_;
        d_ = P12.y - T12.y; sp += d_ * d_;
        l += sp;

        float i0 = iou8(A13.x, A13.y, A13.z, A13.w,  B13.x, B13.y, B13.z, B13.w);
        float i1 = iou8(A14.x, A14.y, A14.z, A14.w,  B14.x, B14.y, B14.z, B14.w);
        bool b1 = i1 > i0;

        float pc = b1 ? P12.w : P12.z;
        float tc = b1 ? T12.w : T12.z;
        float dc = pc - tc;
        l += (1.0f - NOOBJ_) * dc * dc;

        float px = b1 ? A14.x : A13.x,  py = b1 ? A14.y : A13.y;
        float pw = b1 ? A14.z : A13.z,  ph = b1 ? A14.w : A13.w;
        float tx = b1 ? B14.x : B13.x,  ty = b1 ? B14.y : B13.y;
        float tw = b1 ? B14.z : B13.z,  th = b1 ? B14.w : B13.w;
        float bx = px - tx;
        float by = py - ty;
        float bw = sqrtf(pw) - sqrtf(tw);
        float bh = sqrtf(ph) - sqrtf(th);
        l += COORD_ * (bx * bx + by * by + bw * bw + bh * bh);
    }

    // wave (64-lane) shuffle reduction
    #pragma unroll
    for (int off = 32; off > 0; off >>= 1)
        l += __shfl_down(l, off, 64);

    if (lane == 0) s_red[wave] = l;
    __syncthreads();
    if (tid == 0) {
        float tot = s_red[0] + s_red[1] + s_red[2] + s_red[3];
        atomicAdd(out, tot * (1.0f / (float)N_IMG_));
    }
}

extern "C" void kernel_launch(void* const* d_in, const int* in_sizes, int n_in,
                              void* d_out, int out_size, void* d_ws, size_t ws_size,
                              hipStream_t stream) {
    const float* preds   = (const float*)d_in[0];
    const float* targets = (const float*)d_in[1];
    float* out = (float*)d_out;

    // d_out is poisoned 0xAA before every launch; zero it (graph-capture safe)
    hipMemsetAsync(out, 0, sizeof(float) * (size_t)out_size, stream);

    mploss_kernel<<<NBLK, TPB, 0, stream>>>(preds, targets, out);
}